// Round 9
// baseline (489.488 us; speedup 1.0000x reference)
//
#include <hip/hip_runtime.h>
#include <math.h>

#define B    512
#define L    1024
#define K    8
#define NR   512
#define S    20
#define EXT  26
#define SS   (S*S)            // 400
#define PD   24               // padded matrix dim (zero pad is matmul-self-consistent)
#define PDSQ (PD*PD)          // 576
#define ROWF (K*EXT)          // 208 floats per (b,l)
#define BROW (L*ROWF)         // 212992 floats per b

typedef float f4 __attribute__((ext_vector_type(4)));

__device__ __forceinline__ float softplusf(float x) {
    return fmaxf(x, 0.0f) + log1pf(expf(-fabsf(x)));
}

// wave-local ordering fence: per-wave DS ops complete in order on CDNA, so
// for a wave working on its OWN LDS patch this replaces __syncthreads.
__device__ __forceinline__ void wave_fence() {
    __builtin_amdgcn_wave_barrier();
}

// ---------------------------------------------------------------------------
// DIAGNOSTIC ROUND (intentional ~2x store traffic, output still correct):
// every output f4 is stored TWICE (same addr, same value; second store via
// inline asm so it cannot be dead-store-eliminated). Purpose: push this
// kernel's duration above the harness poison-fills so rocprof's top-5 shows
// OUR dispatch with FETCH/WRITE/hbm_gbps/LDS_BANK_CONFLICT/Occupancy.
// Discriminates store-BW-bound (dur ~640, hbm ~2.6 TB/s, WRITE ~852MB)
// vs issue/latency-bound (dur ~520, stores nearly free)
// vs write-amplification/scratch (WRITE >> 852MB or FETCH large).
// Everything except the duplicated store is identical to the r5 kernel
// (verified passed, absmax 1.22e-4, 484us).
// ---------------------------------------------------------------------------
__global__ __launch_bounds__(512, 2) void fused_kernel(
    const int*   __restrict__ inputs,        // B,L
    const int*   __restrict__ rate_indices,  // B
    const float* __restrict__ tau_kernel,    // NR
    const float* __restrict__ exch,          // K,S,S
    const float* __restrict__ freq,          // S
    float* __restrict__ out)                 // B,L,208
{
    __shared__ __align__(16) float M[K][2][PDSQ];   // 36864 B
    __shared__ __align__(16) float Row[EXT*ROWF];   // 21632 B
    __shared__ int   inp_sh[L];                     // 4096 B
    __shared__ float diag_sh[K][S];
    __shared__ float mue_sh[K];

    const int b    = blockIdx.x;
    const int t    = threadIdx.x;
    const int w    = t >> 6;          // wave id == matrix k
    const int lane = t & 63;
    const int li = lane >> 3, lj = lane & 7;
    const int r0 = 3*li, c0 = 3*lj;   // 3x3 tile origin in 24x24

    // ---- phase 0 (no cross-wave ordering needed until the final barrier) ----
    for (int u = t; u < L; u += 512) inp_sh[u] = inputs[b*L + u];
    for (int e = t; e < EXT*ROWF; e += 512) {
        int row = e / ROWF, c = e - row*ROWF;
        int k = c / EXT, s = c - k*EXT;
        (void)k;
        if (row < S) {
            if (s >= S) Row[e] = 0.f;              // pad cols only; P cells skipped
        } else {
            Row[e] = (s == row) ? 1.f : 0.f;       // one-hot rows
        }
    }
    float* M0 = &M[w][0][0];
    float* M1 = &M[w][1][0];
    for (int e = lane; e < 2*PDSQ; e += 64) M0[e] = 0.f;  // zero both buffers
    // tau: uniform loads, computed redundantly in every lane
    float tau = softplusf(tau_kernel[rate_indices[b]]);
    wave_fence();

    // ---- phase 1: build A = (Q_w / mue) * tau / 2^6 in M0 ----
    const float* E = exch + w * SS;
    for (int e = lane; e < SS; e += 64) {
        int r = e / S, c = e - r*S;
        float v = 0.f;
        if (r != c)
            v = softplusf(0.5f * (E[r*S + c] + E[c*S + r])) * freq[c];
        M0[r*PD + c] = v;
    }
    wave_fence();
    if (lane < S) {
        float d = 0.f;
        #pragma unroll
        for (int j = 0; j < S; ++j) d += M0[lane*PD + j];
        diag_sh[w][lane] = d;
    }
    wave_fence();
    if (lane == 0) {
        float m = 0.f;
        #pragma unroll
        for (int s = 0; s < S; ++s) m += freq[s] * diag_sh[w][s];
        mue_sh[w] = fmaxf(m, 1e-16f);
    }
    wave_fence();
    {
        float scale = tau * 0.015625f;
        float mue   = mue_sh[w];
        for (int e = lane; e < SS; e += 64) {
            int r = e / S, c = e - r*S;
            float v = (r == c) ? -diag_sh[w][r] : M0[r*PD + c];
            M0[r*PD + c] = (v / mue) * scale;
        }
    }
    wave_fence();

    // ---- expm: A cols in regs, P=I+A, order-10 Taylor, 6 squarings ----
    float Ac[S][3];
    #pragma unroll
    for (int j = 0; j < S; ++j) {
        #pragma unroll
        for (int d = 0; d < 3; ++d)
            Ac[j][d] = M0[j*PD + c0 + d];
    }

    float P[3][3];
    #pragma unroll
    for (int dr = 0; dr < 3; ++dr)
        #pragma unroll
        for (int dc = 0; dc < 3; ++dc) {
            int r = r0 + dr, c = c0 + dc;
            P[dr][dc] = M0[r*PD + c] + ((r == c && r < S) ? 1.f : 0.f);
        }

    const float* Tc = M0;
    float* Tn = M1;
    #pragma unroll 1
    for (int i = 2; i <= 10; ++i) {
        float C[3][3] = {{0.f,0.f,0.f},{0.f,0.f,0.f},{0.f,0.f,0.f}};
        #pragma unroll
        for (int jc = 0; jc < 5; ++jc) {
            float4 a0 = *(const float4*)&Tc[(r0+0)*PD + 4*jc];
            float4 a1 = *(const float4*)&Tc[(r0+1)*PD + 4*jc];
            float4 a2 = *(const float4*)&Tc[(r0+2)*PD + 4*jc];
            float t0[4] = {a0.x, a0.y, a0.z, a0.w};
            float t1[4] = {a1.x, a1.y, a1.z, a1.w};
            float t2[4] = {a2.x, a2.y, a2.z, a2.w};
            #pragma unroll
            for (int dj = 0; dj < 4; ++dj) {
                int j = 4*jc + dj;
                #pragma unroll
                for (int dc = 0; dc < 3; ++dc) {
                    C[0][dc] = fmaf(t0[dj], Ac[j][dc], C[0][dc]);
                    C[1][dc] = fmaf(t1[dj], Ac[j][dc], C[1][dc]);
                    C[2][dc] = fmaf(t2[dj], Ac[j][dc], C[2][dc]);
                }
            }
        }
        float inv = 1.0f / (float)i;
        #pragma unroll
        for (int dr = 0; dr < 3; ++dr)
            #pragma unroll
            for (int dc = 0; dc < 3; ++dc) {
                C[dr][dc] *= inv;
                P[dr][dc] += C[dr][dc];
                Tn[(r0+dr)*PD + c0 + dc] = C[dr][dc];
            }
        wave_fence();
        float* tmp = (float*)Tc; Tc = Tn; Tn = tmp;
    }

    #pragma unroll 1
    for (int sq = 0; sq < 6; ++sq) {
        #pragma unroll
        for (int dr = 0; dr < 3; ++dr)
            #pragma unroll
            for (int dc = 0; dc < 3; ++dc)
                Tn[(r0+dr)*PD + c0 + dc] = P[dr][dc];
        wave_fence();
        const float* Pb = Tn;
        float C[3][3] = {{0.f,0.f,0.f},{0.f,0.f,0.f},{0.f,0.f,0.f}};
        #pragma unroll
        for (int jc = 0; jc < 5; ++jc) {
            float4 a0 = *(const float4*)&Pb[(r0+0)*PD + 4*jc];
            float4 a1 = *(const float4*)&Pb[(r0+1)*PD + 4*jc];
            float4 a2 = *(const float4*)&Pb[(r0+2)*PD + 4*jc];
            float t0[4] = {a0.x, a0.y, a0.z, a0.w};
            float t1[4] = {a1.x, a1.y, a1.z, a1.w};
            float t2[4] = {a2.x, a2.y, a2.z, a2.w};
            float cb[4][3];
            #pragma unroll
            for (int dj = 0; dj < 4; ++dj)
                #pragma unroll
                for (int dc = 0; dc < 3; ++dc)
                    cb[dj][dc] = Pb[(4*jc + dj)*PD + c0 + dc];
            #pragma unroll
            for (int dj = 0; dj < 4; ++dj)
                #pragma unroll
                for (int dc = 0; dc < 3; ++dc) {
                    C[0][dc] = fmaf(t0[dj], cb[dj][dc], C[0][dc]);
                    C[1][dc] = fmaf(t1[dj], cb[dj][dc], C[1][dc]);
                    C[2][dc] = fmaf(t2[dj], cb[dj][dc], C[2][dc]);
                }
        }
        #pragma unroll
        for (int dr = 0; dr < 3; ++dr)
            #pragma unroll
            for (int dc = 0; dc < 3; ++dc)
                P[dr][dc] = C[dr][dc];
        float* tmp = (float*)Tc; Tc = Tn; Tn = tmp;
        wave_fence();
    }

    // ---- P tiles -> Row LUT (only r<20, c<20 cells; disjoint from init) ----
    #pragma unroll
    for (int dr = 0; dr < 3; ++dr) {
        int r = r0 + dr; if (r >= S) continue;
        #pragma unroll
        for (int dc = 0; dc < 3; ++dc) {
            int c = c0 + dc; if (c >= S) continue;
            Row[r*ROWF + w*EXT + c] = P[dr][dc];
        }
    }
    __syncthreads();   // the ONLY block-wide barrier

    // ---- phase 2: wave-contiguous streaming store, DOUBLED (diagnostic) ----
    // u = i*6656 + w*832 + j*64 + lane  — same bijection as r5. Each f4 is
    // stored twice: once by the compiler, once via inline asm (un-DSE-able).
    int d13[13], qq[13];
    {
        int uu = lane;
        #pragma unroll
        for (int j = 0; j < 13; ++j) {
            d13[j] = uu / 52;
            qq[j] = uu - d13[j] * 52;
            uu += 64;
        }
    }
    const f4* Row4 = (const f4*)Row;
    f4* out4 = (f4*)out + (size_t)b * (BROW/4);
    #pragma unroll 1
    for (int i = 0; i < 8; ++i) {
        int lidx  = (i << 7) + (w << 4);      // i*128 + w*16
        int ubase = i * 6656 + w * 832 + lane;
        #pragma unroll
        for (int j = 0; j < 13; ++j) {
            int inp = inp_sh[lidx + d13[j]];
            f4 v = Row4[inp * 52 + qq[j]];
            f4* p = &out4[ubase + (j << 6)];
            *p = v;                                        // store 1 (normal)
            asm volatile("global_store_dwordx4 %0, %1, off"
                         :: "v"(p), "v"(v) : "memory");    // store 2 (dup)
        }
    }
}

// ---------------------------------------------------------------------------
extern "C" void kernel_launch(void* const* d_in, const int* in_sizes, int n_in,
                              void* d_out, int out_size, void* d_ws, size_t ws_size,
                              hipStream_t stream) {
    const int*   inputs  = (const int*)  d_in[0];  // (B,L) int32
    const int*   rate_ix = (const int*)  d_in[1];  // (B,) int32
    const float* tau_k   = (const float*)d_in[2];  // (NR,) f32
    const float* exch    = (const float*)d_in[3];  // (K,S,S) f32
    const float* freq    = (const float*)d_in[4];  // (S,) f32
    float* out = (float*)d_out;

    (void)d_ws; (void)ws_size; (void)in_sizes; (void)n_in; (void)out_size;

    fused_kernel<<<B, 512, 0, stream>>>(inputs, rate_ix, tau_k, exch, freq, out);
}